// Round 4
// baseline (1127.020 us; speedup 1.0000x reference)
//
#include <hip/hip_runtime.h>
#include <math.h>

// Problem constants (B=8, H=W=128, C=128, R=4 -> 81 cost channels)
#define BATCH 8
#define HH 128
#define WW 128
#define CC 128
#define RR 4
#define DDIM 9
#define NS 81
#define NSP 96          // cost channels padded to 96 (zero-filled 81..95)
#define HWPIX (HH*WW)

typedef short  short8  __attribute__((ext_vector_type(8)));
typedef short  short4v __attribute__((ext_vector_type(4)));
typedef float  f32x4   __attribute__((ext_vector_type(4)));

__device__ __forceinline__ short bf16h(float f){
    unsigned u = __float_as_uint(f);
    u += 0x7fffu + ((u >> 16) & 1u);
    return (short)(u >> 16);
}
__device__ __forceinline__ float bf16f(short s){
    return __uint_as_float(((unsigned)(unsigned short)s) << 16);
}

__device__ __forceinline__ float mish_f(float x){
    float xc = fminf(x, 30.f);
    float t = expf(xc);
    float u = t*t + 2.f*t;
    return x * (u / (u + 2.f));
}

// ---------------------------------------------------------------------------
// Cost volume: 16x16 px tile, nxt halo in LDS, 8-ch chunks, register
// prefetch of next chunk (halo + own prv) so global latency overlaps FMAs.
// Output stride 96, zero-padded (so L0 staging is uniform float4 loads).
// ---------------------------------------------------------------------------
__global__ __launch_bounds__(256,2) void cost_kernel(
    const float* __restrict__ prv, const float* __restrict__ nxt,
    float* __restrict__ cost)
{
    __shared__ float nx[24*24*12];
    const int tid = threadIdx.x;
    const int tx = tid & 15, ty = tid >> 4;
    const int x0 = blockIdx.x*16, y0 = blockIdx.y*16, b = blockIdx.z;

    float acc[NS];
#pragma unroll
    for(int s=0;s<NS;s++) acc[s]=0.f;

    const float* prvp = prv + (((size_t)b*HH + (y0+ty))*WW + (x0+tx))*CC;

    float4 pre[5], pA, pB;
    auto fetch = [&](int c0){
#pragma unroll
        for(int it=0;it<5;it++){
            int e = it*256 + tid;
            float4 v = {0.f,0.f,0.f,0.f};
            if(e < 1152){
                int px = e>>1, hf = e&1;
                int hy = y0 - RR + px/24;
                int hx = x0 - RR + px%24;
                if(hy>=0 && hy<HH && hx>=0 && hx<WW)
                    v = *(const float4*)(nxt + (((size_t)b*HH + hy)*WW + hx)*CC + c0 + hf*4);
            }
            pre[it] = v;
        }
        pA = *(const float4*)(prvp + c0);
        pB = *(const float4*)(prvp + c0 + 4);
    };

    fetch(0);
    for(int c0=0;c0<CC;c0+=8){
        __syncthreads();
#pragma unroll
        for(int it=0;it<5;it++){
            int e = it*256 + tid;
            if(e < 1152){
                int px = e>>1, hf = e&1;
                *(float4*)&nx[px*12 + hf*4] = pre[it];
            }
        }
        float4 A = pA, Bv = pB;
        __syncthreads();
        if(c0+8 < CC) fetch(c0+8);
#pragma unroll
        for(int i=0;i<DDIM;i++){
#pragma unroll
            for(int j=0;j<DDIM;j++){
                const float* q = &nx[((ty+i)*24 + (tx+j))*12];
                float4 n0 = *(const float4*)q;
                float4 n1 = *(const float4*)(q+4);
                float s = acc[i*DDIM+j];
                s = fmaf(A.x,n0.x,s);  s = fmaf(A.y,n0.y,s);
                s = fmaf(A.z,n0.z,s);  s = fmaf(A.w,n0.w,s);
                s = fmaf(Bv.x,n1.x,s); s = fmaf(Bv.y,n1.y,s);
                s = fmaf(Bv.z,n1.z,s); s = fmaf(Bv.w,n1.w,s);
                acc[i*DDIM+j] = s;
            }
        }
    }
    float* op = cost + (((size_t)b*HH + (y0+ty))*WW + (x0+tx))*NSP;
#pragma unroll
    for(int s=0;s<NS;s++) op[s] = acc[s]*(1.f/128.f);
#pragma unroll
    for(int s=NS;s<NSP;s++) op[s] = 0.f;
}

// ---------------------------------------------------------------------------
// Pointwise weight prep: split fp32 pw weights into hi/lo bf16 B-fragment
// slabs: dst[(k8*NP + n)*8 + j], k = k8*8+j, zero-padded to K0/NP.
// remap!=0 (L0): padded-concat k -> ref k (k<81: k, 81..95: zero, >=96: k-15).
// ---------------------------------------------------------------------------
__global__ void prep_pw(const float* __restrict__ src, short* __restrict__ dh,
                        short* __restrict__ dl, int K, int N, int NP, int total,
                        int remap)
{
    int idx = blockIdx.x*256 + threadIdx.x;
    if(idx >= total) return;
    int j  = idx & 7;
    int n  = (idx>>3) % NP;
    int k8 = (idx>>3) / NP;
    int k  = k8*8 + j;
    if(remap) k = (k < 81) ? k : ((k < 96) ? -1 : k - 15);
    float v = (k>=0 && k<K && n<N) ? src[(size_t)k*N + n] : 0.f;
    short h = bf16h(v);
    dh[idx] = h;
    dl[idx] = bf16h(v - bf16f(h));
}

// ---------------------------------------------------------------------------
// Fused depthwise-3x3 (fp32 VALU) + pointwise-1x1 (split-bf16 MFMA, fp32 acc).
// Tile: 16(w) x 8(h) = 128 px, 4 waves in 2(m) x 2(n) grid.  K-chunks of 32.
// Pipelined: next chunk's halo/dw/B fragments prefetched into registers
// right after the current chunk's LDS write, overlapping dw + MFMA.
// CONCAT: virtual input [cost(96, zero-padded) | prv(128) | nxt(128)] = 352;
// each 32-chunk lies in exactly one source -> uniform float4 staging.
// ---------------------------------------------------------------------------
template<int CINR,int K0,int COUT,int NP,bool BIAS,bool ACT,bool CONCAT>
__global__ __launch_bounds__(256,3) void sep_mfma(
    const float* __restrict__ xin, const float* __restrict__ cost,
    const float* __restrict__ prv, const float* __restrict__ nxt,
    const float* __restrict__ dwv, const short* __restrict__ wh,
    const short* __restrict__ wl, const float* __restrict__ bias,
    float* __restrict__ out)
{
    constexpr int TN = NP/32;           // n-tiles per wave (16 couts each)
    __shared__ float xs[180*36];        // halo 10(y) x 18(x), 32 ch, stride 36
    __shared__ short dshh[4*128*8];     // [k8][px][j]  hi
    __shared__ short dshl[4*128*8];     // [k8][px][j]  lo
    __shared__ float dwls[9*32];

    const int tid = threadIdx.x;
    const int x0 = blockIdx.x*16, y0 = blockIdx.y*8, b = blockIdx.z;
    const int lane = tid & 63;
    const int wv   = tid >> 6;
    const int wm   = wv >> 1, wn = wv & 1;
    const int l15  = lane & 15, quad = lane >> 4;

    f32x4 acc[4][TN];
#pragma unroll
    for(int i=0;i<4;i++)
#pragma unroll
        for(int nt=0;nt<TN;nt++) acc[i][nt] = (f32x4){0.f,0.f,0.f,0.f};

    float4 pre[6];
    float  dpre[2];
    short8 Bph[TN], Bpl[TN];

    auto fetch_all = [&](int c0){
        const float* src; int str, coff;
        if(CONCAT){
            if(c0 < 96)      { src = cost; str = NSP; coff = c0; }
            else if(c0 < 224){ src = prv;  str = 128; coff = c0-96; }
            else             { src = nxt;  str = 128; coff = c0-224; }
        } else { src = xin; str = CINR; coff = c0; }
        // halo: 180 px x 8 float4
#pragma unroll
        for(int it=0;it<6;it++){
            int e = it*256 + tid;
            float4 v = {0.f,0.f,0.f,0.f};
            if(e < 1440){
                int hp = e>>3, c4 = e&7;
                int hy = y0-1 + hp/18, hx = x0-1 + hp%18;
                if(hy>=0 && hy<HH && hx>=0 && hx<WW)
                    v = *(const float4*)(src + (((size_t)b*HH + hy)*WW + hx)*str + coff + c4*4);
            }
            pre[it] = v;
        }
        // depthwise weights for this chunk
#pragma unroll
        for(int it=0;it<2;it++){
            int e = it*256 + tid;
            float v = 0.f;
            if(e < 288){
                int k = e>>5, c = e&31, gc = c0 + c;
                if(CONCAT){
                    int cr = (gc < 81) ? gc : ((gc < 96) ? -1 : gc - 15);
                    if(cr >= 0) v = dwv[k*CINR + cr];
                } else v = dwv[k*CINR + gc];
            }
            dpre[it] = v;
        }
        // B fragments (hi/lo) for this chunk
        const int k8 = (c0>>3) + quad;
#pragma unroll
        for(int nt=0;nt<TN;nt++){
            int n = wn*(NP/2) + nt*16 + l15;
            size_t off = ((size_t)k8*NP + n)*8;
            Bph[nt] = *(const short8*)(wh + off);
            Bpl[nt] = *(const short8*)(wl + off);
        }
    };

    fetch_all(0);
    for(int c0=0;c0<K0;c0+=32){
        __syncthreads();
        // ---- write prefetched chunk into LDS ----
#pragma unroll
        for(int it=0;it<6;it++){
            int e = it*256 + tid;
            if(e < 1440){
                int hp = e>>3, c4 = e&7;
                *(float4*)&xs[hp*36 + c4*4] = pre[it];
            }
        }
#pragma unroll
        for(int it=0;it<2;it++){
            int e = it*256 + tid;
            if(e < 288) dwls[e] = dpre[it];
        }
        // consume B registers before they are overwritten by the next fetch
        short8 Bh[TN], Bl[TN];
#pragma unroll
        for(int nt=0;nt<TN;nt++){ Bh[nt]=Bph[nt]; Bl[nt]=Bpl[nt]; }
        __syncthreads();
        if(c0+32 < K0) fetch_all(c0+32);
        // ---- depthwise 3x3 + split to bf16 hi/lo ----
#pragma unroll
        for(int r=0;r<4;r++){
            int idx = r*256 + tid;
            int c4 = idx&7, px = idx>>3;
            int py = px>>4, pxx = px&15;
            float4 s = {0.f,0.f,0.f,0.f};
#pragma unroll
            for(int kh=0;kh<3;kh++)
#pragma unroll
                for(int kw=0;kw<3;kw++){
                    float4 xv = *(const float4*)&xs[((py+kh)*18 + (pxx+kw))*36 + c4*4];
                    float4 wv4= *(const float4*)&dwls[(kh*3+kw)*32 + c4*4];
                    s.x = fmaf(xv.x,wv4.x,s.x); s.y = fmaf(xv.y,wv4.y,s.y);
                    s.z = fmaf(xv.z,wv4.z,s.z); s.w = fmaf(xv.w,wv4.w,s.w);
                }
            short4v h, l;
            h.x=bf16h(s.x); l.x=bf16h(s.x-bf16f(h.x));
            h.y=bf16h(s.y); l.y=bf16h(s.y-bf16f(h.y));
            h.z=bf16h(s.z); l.z=bf16h(s.z-bf16f(h.z));
            h.w=bf16h(s.w); l.w=bf16h(s.w-bf16f(h.w));
            int base = (c4>>1)*1024 + px*8 + (c4&1)*4;
            *(short4v*)&dshh[base] = h;
            *(short4v*)&dshl[base] = l;
        }
        __syncthreads();
        // ---- MFMA: A from LDS, B from prefetched registers ----
        short8 Ah[4], Al[4];
#pragma unroll
        for(int i=0;i<4;i++){
            int ab = quad*1024 + (wm*64 + i*16 + l15)*8;
            Ah[i] = *(const short8*)&dshh[ab];
            Al[i] = *(const short8*)&dshl[ab];
        }
#pragma unroll
        for(int i=0;i<4;i++)
#pragma unroll
            for(int nt=0;nt<TN;nt++){
                f32x4 c = acc[i][nt];
                c = __builtin_amdgcn_mfma_f32_16x16x32_bf16(Ah[i],Bh[nt],c,0,0,0);
                c = __builtin_amdgcn_mfma_f32_16x16x32_bf16(Al[i],Bh[nt],c,0,0,0);
                c = __builtin_amdgcn_mfma_f32_16x16x32_bf16(Ah[i],Bl[nt],c,0,0,0);
                acc[i][nt] = c;
            }
    }
    // ---- epilogue: bias + mish + store ----
#pragma unroll
    for(int i=0;i<4;i++){
        int pxb = wm*64 + i*16 + quad*4;
#pragma unroll
        for(int nt=0;nt<TN;nt++){
            int cout = wn*(NP/2) + nt*16 + l15;
            if(cout < COUT){
                float bv = BIAS ? bias[cout] : 0.f;
#pragma unroll
                for(int r=0;r<4;r++){
                    int p = pxb + r;
                    int y = y0 + (p>>4), x = x0 + (p&15);
                    float v = acc[i][nt][r] + bv;
                    if(ACT) v = mish_f(v);
                    out[(((size_t)b*HH + y)*WW + x)*COUT + cout] = v;
                }
            }
        }
    }
}

// ---------------------------------------------------------------------------
extern "C" void kernel_launch(void* const* d_in, const int* in_sizes, int n_in,
                              void* d_out, int out_size, void* d_ws, size_t ws_size,
                              hipStream_t stream)
{
    (void)in_sizes; (void)n_in; (void)out_size;
    const float* prv = (const float*)d_in[0];
    const float* nxt = (const float*)d_in[1];
    const float* dw0 = (const float*)d_in[2];
    const float* pw0 = (const float*)d_in[3];
    const float* b0  = (const float*)d_in[4];
    const float* dw1 = (const float*)d_in[5];
    const float* pw1 = (const float*)d_in[6];
    const float* b1  = (const float*)d_in[7];
    const float* dw2 = (const float*)d_in[8];
    const float* pw2 = (const float*)d_in[9];
    const float* b2  = (const float*)d_in[10];
    const float* dw3 = (const float*)d_in[11];
    const float* pw3 = (const float*)d_in[12];
    const float* b3  = (const float*)d_in[13];
    const float* dw4 = (const float*)d_in[14];
    const float* pw4 = (const float*)d_in[15];
    const float* b4  = (const float*)d_in[16];
    const float* dw5 = (const float*)d_in[17];
    const float* pw5 = (const float*)d_in[18];

    // ---- weight slabs (hi/lo bf16, B-fragment layout) at start of ws ----
    const int   Ks[6]   = {337,128,128, 96, 64, 32};
    const int   K0s[6]  = {352,128,128, 96, 64, 32};
    const int   Ns[6]   = {128,128, 96, 64, 32,  2};
    const int   NPs[6]  = {128,128, 96, 64, 32, 32};
    const int   rmp[6]  = {  1,  0,  0,  0,  0,  0};
    const float* pws[6] = {pw0,pw1,pw2,pw3,pw4,pw5};
    size_t offs[6]; size_t E = 0;
    for(int i=0;i<6;i++){ offs[i] = E; E += (size_t)K0s[i]*NPs[i]; }
    short* Whs = (short*)d_ws;
    short* Wls = Whs + E;
    size_t wbytes = ((E*2*sizeof(short)) + 255) & ~(size_t)255;

    for(int i=0;i<6;i++){
        int total = K0s[i]*NPs[i];
        prep_pw<<<(total+255)/256,256,0,stream>>>(pws[i], Whs+offs[i], Wls+offs[i],
                                                  Ks[i], Ns[i], NPs[i], total, rmp[i]);
    }

    // ---- activation buffers, batch-chunked ----
    const size_t per_batch_floats = (size_t)HWPIX * (NSP + 128 + 128);
    size_t avail = (ws_size > wbytes) ? (ws_size - wbytes) : 0;
    int NB = (int)(avail / (per_batch_floats * sizeof(float)));
    if(NB > BATCH) NB = BATCH;
    if(NB < 1)     NB = 1;
    while(BATCH % NB) NB--;

    float* fbase = (float*)((char*)d_ws + wbytes);
    float* costb = fbase;
    float* bufA  = costb + (size_t)NB*HWPIX*NSP;
    float* bufB  = bufA  + (size_t)NB*HWPIX*128;

    for(int bb=0; bb<BATCH; bb+=NB){
        const float* prv_o = prv + (size_t)bb*HWPIX*CC;
        const float* nxt_o = nxt + (size_t)bb*HWPIX*CC;
        float*       out_o = (float*)d_out + (size_t)bb*HWPIX*2;
        dim3 gc(WW/16, HH/16, NB);
        dim3 gs(WW/16, HH/8,  NB);

        cost_kernel<<<gc,256,0,stream>>>(prv_o, nxt_o, costb);
        sep_mfma<337,352,128,128,true ,true ,true ><<<gs,256,0,stream>>>(nullptr, costb, prv_o, nxt_o, dw0, Whs+offs[0], Wls+offs[0], b0, bufA);
        sep_mfma<128,128,128,128,true ,true ,false><<<gs,256,0,stream>>>(bufA, nullptr,nullptr,nullptr, dw1, Whs+offs[1], Wls+offs[1], b1, bufB);
        sep_mfma<128,128, 96, 96,true ,true ,false><<<gs,256,0,stream>>>(bufB, nullptr,nullptr,nullptr, dw2, Whs+offs[2], Wls+offs[2], b2, bufA);
        sep_mfma< 96, 96, 64, 64,true ,true ,false><<<gs,256,0,stream>>>(bufA, nullptr,nullptr,nullptr, dw3, Whs+offs[3], Wls+offs[3], b3, bufB);
        sep_mfma< 64, 64, 32, 32,true ,true ,false><<<gs,256,0,stream>>>(bufB, nullptr,nullptr,nullptr, dw4, Whs+offs[4], Wls+offs[4], b4, bufA);
        sep_mfma< 32, 32,  2, 32,false,false,false><<<gs,256,0,stream>>>(bufA, nullptr,nullptr,nullptr, dw5, Whs+offs[5], Wls+offs[5], nullptr, out_o);
    }
}

// Round 6
// 772.973 us; speedup vs baseline: 1.4580x; 1.4580x over previous
//
#include <hip/hip_runtime.h>
#include <math.h>

// Problem constants (B=8, H=W=128, C=128, R=4 -> 81 cost channels)
#define BATCH 8
#define HH 128
#define WW 128
#define CC 128
#define RR 4
#define DDIM 9
#define NS 81
#define NSP 96          // cost channels padded to 96 (zero-filled 81..95)
#define HWPIX (HH*WW)

typedef short  short8  __attribute__((ext_vector_type(8)));
typedef float  f32x4   __attribute__((ext_vector_type(4)));

__device__ __forceinline__ short bf16h(float f){
    unsigned u = __float_as_uint(f);
    u += 0x7fffu + ((u >> 16) & 1u);
    return (short)(u >> 16);
}
__device__ __forceinline__ float bf16f(short s){
    return __uint_as_float(((unsigned)(unsigned short)s) << 16);
}
__device__ __forceinline__ float mish_f(float x){
    float xc = fminf(x, 30.f);
    float t = expf(xc);
    float u = t*t + 2.f*t;
    return x * (u / (u + 2.f));
}

// async global->LDS DMA, 16 B/lane.  HW semantics: LDS dest = readfirstlane
// (first ACTIVE lane's pointer) + lane*16.  => call sites must keep lane 0 of
// each wave active (prefix-only masking) and give OOB lanes a SAFE global
// address (zero scratch) instead of exec-masking them out.  (r5 abort lesson.)
__device__ __forceinline__ void gld16(float* lds, const float* g){
    __builtin_amdgcn_global_load_lds(
        (const __attribute__((address_space(1))) unsigned int*)g,
        (__attribute__((address_space(3))) unsigned int*)lds, 16, 0, 0);
}

__global__ void zero_k(float* p, int n){
    int i = blockIdx.x*256 + threadIdx.x;
    if(i < n) p[i] = 0.f;
}

// ---------------------------------------------------------------------------
// Cost volume: 16x16 px tile, nxt halo staged via global_load_lds into
// stride-12 rows (8 used floats + 4 pad; pad/OOB slots DMA from zero
// scratch).  Output stride 96, zero-padded channels 81..95.
// ---------------------------------------------------------------------------
__global__ __launch_bounds__(256,3) void cost_kernel(
    const float* __restrict__ prv, const float* __restrict__ nxt,
    const float* __restrict__ zb, float* __restrict__ cost)
{
    __shared__ float nx[576*12];
    const int tid = threadIdx.x;
    const int tx = tid & 15, ty = tid >> 4;
    const int x0 = blockIdx.x*16, y0 = blockIdx.y*16, b = blockIdx.z;

    float acc[NS];
#pragma unroll
    for(int s=0;s<NS;s++) acc[s]=0.f;

    const float* prvp = prv + (((size_t)b*HH + (y0+ty))*WW + (x0+tx))*CC;
    const float* nxb  = nxt + (size_t)b*HH*WW*CC;

    for(int c0=0;c0<CC;c0+=8){
        float4 A  = *(const float4*)(prvp + c0);      // ready at barrier
        float4 Bv = *(const float4*)(prvp + c0 + 4);
        // stage halo: 576 rows x 3 dwordx4 (slot 2 = pad -> zero scratch)
#pragma unroll
        for(int it=0;it<7;it++){
            int e = it*256 + tid;
            if(e < 1728){                               // prefix mask only
                int px = e/3, q = e - px*3;
                int hy = y0 - RR + px/24, hx = x0 - RR + px%24;
                bool ok = (q < 2) && hy>=0 && hy<HH && hx>=0 && hx<WW;
                const float* gp = ok ? (nxb + ((size_t)hy*WW + hx)*CC + c0 + q*4)
                                     : zb;
                gld16(&nx[px*12 + q*4], gp);
            }
        }
        __syncthreads();          // DMA landed
#pragma unroll
        for(int i=0;i<DDIM;i++){
#pragma unroll
            for(int j=0;j<DDIM;j++){
                const float* q = &nx[((ty+i)*24 + (tx+j))*12];
                float4 n0 = *(const float4*)q;
                float4 n1 = *(const float4*)(q+4);
                float s = acc[i*DDIM+j];
                s = fmaf(A.x,n0.x,s);  s = fmaf(A.y,n0.y,s);
                s = fmaf(A.z,n0.z,s);  s = fmaf(A.w,n0.w,s);
                s = fmaf(Bv.x,n1.x,s); s = fmaf(Bv.y,n1.y,s);
                s = fmaf(Bv.z,n1.z,s); s = fmaf(Bv.w,n1.w,s);
                acc[i*DDIM+j] = s;
            }
        }
        __syncthreads();          // reads done before next chunk's DMA
    }
    float* op = cost + (((size_t)b*HH + (y0+ty))*WW + (x0+tx))*NSP;
#pragma unroll
    for(int s=0;s<NS;s++) op[s] = acc[s]*(1.f/128.f);
#pragma unroll
    for(int s=NS;s<NSP;s++) op[s] = 0.f;
}

// ---------------------------------------------------------------------------
// Pointwise weight prep (hi/lo bf16 B-fragment slabs), remap for padded concat.
// ---------------------------------------------------------------------------
__global__ void prep_pw(const float* __restrict__ src, short* __restrict__ dh,
                        short* __restrict__ dl, int K, int N, int NP, int total,
                        int remap)
{
    int idx = blockIdx.x*256 + threadIdx.x;
    if(idx >= total) return;
    int j  = idx & 7;
    int n  = (idx>>3) % NP;
    int k8 = (idx>>3) / NP;
    int k  = k8*8 + j;
    if(remap) k = (k < 81) ? k : ((k < 96) ? -1 : k - 15);
    float v = (k>=0 && k<K && n<N) ? src[(size_t)k*N + n] : 0.f;
    short h = bf16h(v);
    dh[idx] = h;
    dl[idx] = bf16h(v - bf16f(h));
}

// Depthwise weight prep: [9][K0] slab, remapped/zero-padded.
__global__ void prep_dw(const float* __restrict__ src, float* __restrict__ dst,
                        int K, int K0, int remap, int total)
{
    int idx = blockIdx.x*256 + threadIdx.x;
    if(idx >= total) return;
    int k = idx / K0, c = idx - k*K0;
    int cr = c;
    if(remap) cr = (c < 81) ? c : ((c < 96) ? -1 : c - 15);
    dst[idx] = (cr>=0 && cr<K) ? src[k*K + cr] : 0.f;
}

// ---------------------------------------------------------------------------
// Fused depthwise-3x3 (fp32 VALU) + pointwise-1x1 (split-bf16 MFMA, fp32 acc).
// Tile: 16(w) x 8(h) = 128 px, 4 waves in 2(m) x 2(n) grid.  K-chunks of 32.
// Halo staged via global_load_lds into stride-36 rows (32 used floats + 4
// pad; pad/OOB lanes DMA from zero scratch).  dw weights DMA'd from prepped
// slab.  B fragments plain-loaded at loop top (ready at the barrier).
// ---------------------------------------------------------------------------
template<int CINR,int K0,int COUT,int NP,bool BIAS,bool ACT,bool CONCAT>
__global__ __launch_bounds__(256,3) void sep_mfma(
    const float* __restrict__ xin, const float* __restrict__ cost,
    const float* __restrict__ prv, const float* __restrict__ nxt,
    const float* __restrict__ dwp, const short* __restrict__ wh,
    const short* __restrict__ wl, const float* __restrict__ bias,
    const float* __restrict__ zb, float* __restrict__ out)
{
    constexpr int TN = NP/32;           // n-tiles per wave (16 couts each)
    __shared__ float xs[180*36];        // halo 10(y) x 18(x), stride 36
    __shared__ short dshh[4*128*8];     // [k8][px][j]  hi
    __shared__ short dshl[4*128*8];     // [k8][px][j]  lo
    __shared__ float dwls[9*32];

    const int tid = threadIdx.x;
    const int x0 = blockIdx.x*16, y0 = blockIdx.y*8, b = blockIdx.z;
    const int lane = tid & 63;
    const int wv   = tid >> 6;
    const int wm   = wv >> 1, wn = wv & 1;
    const int l15  = lane & 15, quad = lane >> 4;

    f32x4 acc[4][TN];
#pragma unroll
    for(int i=0;i<4;i++)
#pragma unroll
        for(int nt=0;nt<TN;nt++) acc[i][nt] = (f32x4){0.f,0.f,0.f,0.f};

    for(int c0=0;c0<K0;c0+=32){
        // ---- B fragments (plain loads; ready at the barrier) ----
        const int k8 = (c0>>3) + quad;
        short8 Bh[TN], Bl[TN];
#pragma unroll
        for(int nt=0;nt<TN;nt++){
            int n = wn*(NP/2) + nt*16 + l15;
            size_t off = ((size_t)k8*NP + n)*8;
            Bh[nt] = *(const short8*)(wh + off);
            Bl[nt] = *(const short8*)(wl + off);
        }
        // ---- dw chunk DMA: 9 rows x 8 dwordx4 (prefix mask, in-bounds) ----
        if(tid < 72)
            gld16(&dwls[(tid>>3)*32 + (tid&7)*4],
                  dwp + (tid>>3)*K0 + c0 + (tid&7)*4);
        // ---- halo DMA: 180 rows x 9 dwordx4 (slot 8 = pad -> zero) ----
        const float* src; int str, coff;
        if(CONCAT){
            if(c0 < 96)      { src = cost; str = NSP; coff = c0; }
            else if(c0 < 224){ src = prv;  str = 128; coff = c0-96; }
            else             { src = nxt;  str = 128; coff = c0-224; }
        } else { src = xin; str = CINR; coff = c0; }
        const float* sb = src + (size_t)b*HH*WW*str + coff;
#pragma unroll
        for(int it=0;it<7;it++){
            int e = it*256 + tid;
            if(e < 1620){                               // prefix mask only
                int hp = e/9, q = e - hp*9;
                int hy = y0-1 + hp/18, hx = x0-1 + hp%18;
                bool ok = (q < 8) && hy>=0 && hy<HH && hx>=0 && hx<WW;
                const float* gp = ok ? (sb + ((size_t)hy*WW + hx)*str + q*4)
                                     : zb;
                gld16(&xs[hp*36 + q*4], gp);
            }
        }
        __syncthreads();   // A: DMA + B loads landed
        // ---- depthwise 3x3 + split to bf16 hi/lo ----
#pragma unroll
        for(int r=0;r<4;r++){
            int idx = r*256 + tid;
            int c4 = idx&7, px = idx>>3;
            int py = px>>4, pxx = px&15;
            float4 s = {0.f,0.f,0.f,0.f};
#pragma unroll
            for(int kh=0;kh<3;kh++)
#pragma unroll
                for(int kw=0;kw<3;kw++){
                    float4 xv = *(const float4*)&xs[((py+kh)*18 + (pxx+kw))*36 + c4*4];
                    float4 wv4= *(const float4*)&dwls[(kh*3+kw)*32 + c4*4];
                    s.x = fmaf(xv.x,wv4.x,s.x); s.y = fmaf(xv.y,wv4.y,s.y);
                    s.z = fmaf(xv.z,wv4.z,s.z); s.w = fmaf(xv.w,wv4.w,s.w);
                }
            short h0=bf16h(s.x), h1=bf16h(s.y), h2=bf16h(s.z), h3=bf16h(s.w);
            short l0=bf16h(s.x-bf16f(h0)), l1=bf16h(s.y-bf16f(h1));
            short l2=bf16h(s.z-bf16f(h2)), l3=bf16h(s.w-bf16f(h3));
            int base = (c4>>1)*1024 + px*8 + (c4&1)*4;
            *(short4*)&dshh[base] = make_short4(h0,h1,h2,h3);
            *(short4*)&dshl[base] = make_short4(l0,l1,l2,l3);
        }
        __syncthreads();   // B: dsh ready
        // ---- MFMA: A from LDS, B from registers ----
#pragma unroll
        for(int i=0;i<4;i++){
            int ab = quad*1024 + (wm*64 + i*16 + l15)*8;
            short8 Ah = *(const short8*)&dshh[ab];
            short8 Al = *(const short8*)&dshl[ab];
#pragma unroll
            for(int nt=0;nt<TN;nt++){
                f32x4 c = acc[i][nt];
                c = __builtin_amdgcn_mfma_f32_16x16x32_bf16(Ah,Bh[nt],c,0,0,0);
                c = __builtin_amdgcn_mfma_f32_16x16x32_bf16(Al,Bh[nt],c,0,0,0);
                c = __builtin_amdgcn_mfma_f32_16x16x32_bf16(Ah,Bl[nt],c,0,0,0);
                acc[i][nt] = c;
            }
        }
    }
    // ---- epilogue: bias + mish + store ----
#pragma unroll
    for(int i=0;i<4;i++){
        int pxb = wm*64 + i*16 + quad*4;
#pragma unroll
        for(int nt=0;nt<TN;nt++){
            int cout = wn*(NP/2) + nt*16 + l15;
            if(cout < COUT){
                float bv = BIAS ? bias[cout] : 0.f;
#pragma unroll
                for(int r=0;r<4;r++){
                    int p = pxb + r;
                    int y = y0 + (p>>4), x = x0 + (p&15);
                    float v = acc[i][nt][r] + bv;
                    if(ACT) v = mish_f(v);
                    out[(((size_t)b*HH + y)*WW + x)*COUT + cout] = v;
                }
            }
        }
    }
}

// ---------------------------------------------------------------------------
extern "C" void kernel_launch(void* const* d_in, const int* in_sizes, int n_in,
                              void* d_out, int out_size, void* d_ws, size_t ws_size,
                              hipStream_t stream)
{
    (void)in_sizes; (void)n_in; (void)out_size;
    const float* prv = (const float*)d_in[0];
    const float* nxt = (const float*)d_in[1];
    const float* dws[6] = {(const float*)d_in[2],(const float*)d_in[5],(const float*)d_in[8],
                           (const float*)d_in[11],(const float*)d_in[14],(const float*)d_in[17]};
    const float* pws[6] = {(const float*)d_in[3],(const float*)d_in[6],(const float*)d_in[9],
                           (const float*)d_in[12],(const float*)d_in[15],(const float*)d_in[18]};
    const float* b0  = (const float*)d_in[4];
    const float* b1  = (const float*)d_in[7];
    const float* b2  = (const float*)d_in[10];
    const float* b3  = (const float*)d_in[13];
    const float* b4  = (const float*)d_in[16];

    // ---- weight slabs: pw hi/lo bf16 + dw fp32 [9][K0] + zero scratch ----
    const int   Ks[6]   = {337,128,128, 96, 64, 32};
    const int   K0s[6]  = {352,128,128, 96, 64, 32};
    const int   Ns[6]   = {128,128, 96, 64, 32,  2};
    const int   NPs[6]  = {128,128, 96, 64, 32, 32};
    const int   rmp[6]  = {  1,  0,  0,  0,  0,  0};
    size_t offs[6]; size_t E = 0;
    for(int i=0;i<6;i++){ offs[i] = E; E += (size_t)K0s[i]*NPs[i]; }
    size_t dwoffs[6]; size_t Edw = 0;
    for(int i=0;i<6;i++){ dwoffs[i] = Edw; Edw += (size_t)9*K0s[i]; }

    short* Whs = (short*)d_ws;
    short* Wls = Whs + E;
    float* Dwp = (float*)((char*)d_ws + ((E*2*sizeof(short) + 255) & ~(size_t)255));
    float* Zb  = Dwp + Edw;                    // 64-float zero scratch
    size_t wbytes = (((char*)(Zb + 64) - (char*)d_ws) + 255) & ~(size_t)255;

    zero_k<<<1,64,0,stream>>>(Zb, 64);
    for(int i=0;i<6;i++){
        int total = K0s[i]*NPs[i];
        prep_pw<<<(total+255)/256,256,0,stream>>>(pws[i], Whs+offs[i], Wls+offs[i],
                                                  Ks[i], Ns[i], NPs[i], total, rmp[i]);
        int tdw = 9*K0s[i];
        prep_dw<<<(tdw+255)/256,256,0,stream>>>(dws[i], Dwp+dwoffs[i],
                                                Ks[i], K0s[i], rmp[i], tdw);
    }

    // ---- activation buffers, batch-chunked ----
    const size_t per_batch_floats = (size_t)HWPIX * (NSP + 128 + 128);
    size_t avail = (ws_size > wbytes) ? (ws_size - wbytes) : 0;
    int NB = (int)(avail / (per_batch_floats * sizeof(float)));
    if(NB > BATCH) NB = BATCH;
    if(NB < 1)     NB = 1;
    while(BATCH % NB) NB--;

    float* fbase = (float*)((char*)d_ws + wbytes);
    float* costb = fbase;
    float* bufA  = costb + (size_t)NB*HWPIX*NSP;
    float* bufB  = bufA  + (size_t)NB*HWPIX*128;

    for(int bb=0; bb<BATCH; bb+=NB){
        const float* prv_o = prv + (size_t)bb*HWPIX*CC;
        const float* nxt_o = nxt + (size_t)bb*HWPIX*CC;
        float*       out_o = (float*)d_out + (size_t)bb*HWPIX*2;
        dim3 gc(WW/16, HH/16, NB);
        dim3 gs(WW/16, HH/8,  NB);

        cost_kernel<<<gc,256,0,stream>>>(prv_o, nxt_o, Zb, costb);
        sep_mfma<337,352,128,128,true ,true ,true ><<<gs,256,0,stream>>>(nullptr, costb, prv_o, nxt_o, Dwp+dwoffs[0], Whs+offs[0], Wls+offs[0], b0, Zb, bufA);
        sep_mfma<128,128,128,128,true ,true ,false><<<gs,256,0,stream>>>(bufA, nullptr,nullptr,nullptr, Dwp+dwoffs[1], Whs+offs[1], Wls+offs[1], b1, Zb, bufB);
        sep_mfma<128,128, 96, 96,true ,true ,false><<<gs,256,0,stream>>>(bufB, nullptr,nullptr,nullptr, Dwp+dwoffs[2], Whs+offs[2], Wls+offs[2], b2, Zb, bufA);
        sep_mfma< 96, 96, 64, 64,true ,true ,false><<<gs,256,0,stream>>>(bufA, nullptr,nullptr,nullptr, Dwp+dwoffs[3], Whs+offs[3], Wls+offs[3], b3, Zb, bufB);
        sep_mfma< 64, 64, 32, 32,true ,true ,false><<<gs,256,0,stream>>>(bufB, nullptr,nullptr,nullptr, Dwp+dwoffs[4], Whs+offs[4], Wls+offs[4], b4, Zb, bufA);
        sep_mfma< 32, 32,  2, 32,false,false,false><<<gs,256,0,stream>>>(bufA, nullptr,nullptr,nullptr, Dwp+dwoffs[5], Whs+offs[5], Wls+offs[5], nullptr, Zb, out_o);
    }
}

// Round 7
// 606.920 us; speedup vs baseline: 1.8570x; 1.2736x over previous
//
#include <hip/hip_runtime.h>
#include <math.h>

// Problem constants (B=8, H=W=128, C=128, R=4 -> 81 cost channels)
#define BATCH 8
#define HH 128
#define WW 128
#define CC 128
#define RR 4
#define DDIM 9
#define NS 81
#define NSP 96          // cost channels padded to 96 (zero-filled 81..95)
#define HWPIX (HH*WW)

typedef short  short8  __attribute__((ext_vector_type(8)));
typedef float  f32x4   __attribute__((ext_vector_type(4)));

__device__ __forceinline__ short bf16h(float f){
    unsigned u = __float_as_uint(f);
    u += 0x7fffu + ((u >> 16) & 1u);
    return (short)(u >> 16);
}
__device__ __forceinline__ float bf16f(short s){
    return __uint_as_float(((unsigned)(unsigned short)s) << 16);
}
__device__ __forceinline__ float mish_f(float x){
    float xc = fminf(x, 30.f);
    float t = expf(xc);
    float u = t*t + 2.f*t;
    return x * (u / (u + 2.f));
}

// async global->LDS DMA, 16 B/lane.  LDS dest = first-active-lane base +
// lane*16 => prefix-only masking, OOB lanes read a zero-scratch global addr.
__device__ __forceinline__ void gld16(float* lds, const float* g){
    __builtin_amdgcn_global_load_lds(
        (const __attribute__((address_space(1))) unsigned int*)g,
        (__attribute__((address_space(3))) unsigned int*)lds, 16, 0, 0);
}

// LDS-only barrier: orders ds_write/ds_read without draining vmcnt, so
// in-flight prefetch DMA keeps flying across it.
__device__ __forceinline__ void lds_barrier(){
    __asm volatile("s_waitcnt lgkmcnt(0)\n\ts_barrier" ::: "memory");
}

__global__ void zero_k(float* p, int n){
    int i = blockIdx.x*256 + threadIdx.x;
    if(i < n) p[i] = 0.f;
}

// ---------------------------------------------------------------------------
// Cost volume: 16x16 px tile, nxt halo DMA'd into double-buffered stride-12
// rows; next chunk's DMA + prv prefetch issued right after the single
// per-chunk barrier -> latency overlapped by the 648-FMA compute phase.
// ---------------------------------------------------------------------------
__global__ __launch_bounds__(256,2) void cost_kernel(
    const float* __restrict__ prv, const float* __restrict__ nxt,
    const float* __restrict__ zb, float* __restrict__ cost)
{
    __shared__ float nx[2][576*12];
    const int tid = threadIdx.x;
    const int tx = tid & 15, ty = tid >> 4;
    const int x0 = blockIdx.x*16, y0 = blockIdx.y*16, b = blockIdx.z;

    float acc[NS];
#pragma unroll
    for(int s=0;s<NS;s++) acc[s]=0.f;

    const float* prvp = prv + (((size_t)b*HH + (y0+ty))*WW + (x0+tx))*CC;
    const float* nxb  = nxt + (size_t)b*HH*WW*CC;

    auto stagec = [&](int c0, int pb){
        float* xp = &nx[pb][0];
#pragma unroll
        for(int it=0;it<7;it++){
            int e = it*256 + tid;
            if(e < 1728){                               // prefix mask only
                int px = e/3, q = e - px*3;
                int hy = y0 - RR + px/24, hx = x0 - RR + px%24;
                bool ok = (q < 2) && hy>=0 && hy<HH && hx>=0 && hx<WW;
                const float* gp = ok ? (nxb + ((size_t)hy*WW + hx)*CC + c0 + q*4)
                                     : zb;
                gld16(xp + px*12 + q*4, gp);
            }
        }
    };

    float4 pAr = *(const float4*)(prvp);
    float4 pBr = *(const float4*)(prvp + 4);
    stagec(0, 0);
    int pb = 0;
    for(int c0=0;c0<CC;c0+=8){
        __syncthreads();              // drains DMA for this chunk (+ prv regs)
        float4 A = pAr, Bv = pBr;
        if(c0+8 < CC){
            pAr = *(const float4*)(prvp + c0 + 8);   // plain loads first...
            pBr = *(const float4*)(prvp + c0 + 12);
            stagec(c0+8, pb^1);                      // ...then prefetch DMA
        }
        const float* xp = &nx[pb][0];
#pragma unroll
        for(int i=0;i<DDIM;i++){
#pragma unroll
            for(int j=0;j<DDIM;j++){
                const float* q = &xp[((ty+i)*24 + (tx+j))*12];
                float4 n0 = *(const float4*)q;
                float4 n1 = *(const float4*)(q+4);
                float s = acc[i*DDIM+j];
                s = fmaf(A.x,n0.x,s);  s = fmaf(A.y,n0.y,s);
                s = fmaf(A.z,n0.z,s);  s = fmaf(A.w,n0.w,s);
                s = fmaf(Bv.x,n1.x,s); s = fmaf(Bv.y,n1.y,s);
                s = fmaf(Bv.z,n1.z,s); s = fmaf(Bv.w,n1.w,s);
                acc[i*DDIM+j] = s;
            }
        }
        pb ^= 1;
    }
    float* op = cost + (((size_t)b*HH + (y0+ty))*WW + (x0+tx))*NSP;
#pragma unroll
    for(int s=0;s<NS;s++) op[s] = acc[s]*(1.f/128.f);
#pragma unroll
    for(int s=NS;s<NSP;s++) op[s] = 0.f;
}

// ---------------------------------------------------------------------------
// Pointwise weight prep (hi/lo bf16 B-fragment slabs), remap for padded concat.
// ---------------------------------------------------------------------------
__global__ void prep_pw(const float* __restrict__ src, short* __restrict__ dh,
                        short* __restrict__ dl, int K, int N, int NP, int total,
                        int remap)
{
    int idx = blockIdx.x*256 + threadIdx.x;
    if(idx >= total) return;
    int j  = idx & 7;
    int n  = (idx>>3) % NP;
    int k8 = (idx>>3) / NP;
    int k  = k8*8 + j;
    if(remap) k = (k < 81) ? k : ((k < 96) ? -1 : k - 15);
    float v = (k>=0 && k<K && n<N) ? src[(size_t)k*N + n] : 0.f;
    short h = bf16h(v);
    dh[idx] = h;
    dl[idx] = bf16h(v - bf16f(h));
}

// Depthwise weight prep: [9][K0] slab, remapped/zero-padded.
__global__ void prep_dw(const float* __restrict__ src, float* __restrict__ dst,
                        int K, int K0, int remap, int total)
{
    int idx = blockIdx.x*256 + threadIdx.x;
    if(idx >= total) return;
    int k = idx / K0, c = idx - k*K0;
    int cr = c;
    if(remap) cr = (c < 81) ? c : ((c < 96) ? -1 : c - 15);
    dst[idx] = (cr>=0 && cr<K) ? src[k*K + cr] : 0.f;
}

// ---------------------------------------------------------------------------
// Fused depthwise-3x3 (fp32 VALU) + pointwise-1x1 (split-bf16 MFMA, fp32 acc).
// Tile 16x8 px, 4 waves 2(m)x2(n).  K-chunks of 32, double-buffered DMA
// staging; chunk k+1's DMA issued after chunk k's opening barrier (overlaps
// depthwise+MFMA of chunk k); lgkm-only mid barrier keeps the prefetch
// in flight through the MFMA phase.  B frags plain-loaded after the opening
// barrier, before the DMA issue (vmcnt-FIFO: waiting on B never drains DMA).
// ---------------------------------------------------------------------------
template<int CINR,int K0,int COUT,int NP,bool BIAS,bool ACT,bool CONCAT>
__global__ __launch_bounds__(256,2) void sep_mfma(
    const float* __restrict__ xin, const float* __restrict__ cost,
    const float* __restrict__ prv, const float* __restrict__ nxt,
    const float* __restrict__ dwp, const short* __restrict__ wh,
    const short* __restrict__ wl, const float* __restrict__ bias,
    const float* __restrict__ zb, float* __restrict__ out)
{
    constexpr int TN = NP/32;           // n-tiles per wave (16 couts each)
    __shared__ float xs[2][180*36];     // halo 10(y) x 18(x), stride 36
    __shared__ short dshh[4*128*8];     // [k8][px][j]  hi
    __shared__ short dshl[4*128*8];     // [k8][px][j]  lo
    __shared__ float dwls[2][9*32];

    const int tid = threadIdx.x;
    const int x0 = blockIdx.x*16, y0 = blockIdx.y*8, b = blockIdx.z;
    const int lane = tid & 63;
    const int wv   = tid >> 6;
    const int wm   = wv >> 1, wn = wv & 1;
    const int l15  = lane & 15, quad = lane >> 4;

    f32x4 acc[4][TN];
#pragma unroll
    for(int i=0;i<4;i++)
#pragma unroll
        for(int nt=0;nt<TN;nt++) acc[i][nt] = (f32x4){0.f,0.f,0.f,0.f};

    auto stage = [&](int c0, int pb){
        if(tid < 72)
            gld16(&dwls[pb][(tid>>3)*32 + (tid&7)*4],
                  dwp + (tid>>3)*K0 + c0 + (tid&7)*4);
        const float* src; int str, coff;
        if(CONCAT){
            if(c0 < 96)      { src = cost; str = NSP; coff = c0; }
            else if(c0 < 224){ src = prv;  str = 128; coff = c0-96; }
            else             { src = nxt;  str = 128; coff = c0-224; }
        } else { src = xin; str = CINR; coff = c0; }
        const float* sb = src + (size_t)b*HH*WW*str + coff;
        float* xp = &xs[pb][0];
#pragma unroll
        for(int it=0;it<7;it++){
            int e = it*256 + tid;
            if(e < 1620){                               // prefix mask only
                int hp = e/9, q = e - hp*9;
                int hy = y0-1 + hp/18, hx = x0-1 + hp%18;
                bool ok = (q < 8) && hy>=0 && hy<HH && hx>=0 && hx<WW;
                const float* gp = ok ? (sb + ((size_t)hy*WW + hx)*str + q*4)
                                     : zb;
                gld16(xp + hp*36 + q*4, gp);
            }
        }
    };

    stage(0, 0);
    int pb = 0;
    for(int c0=0;c0<K0;c0+=32){
        __syncthreads();   // drains this chunk's DMA (issued last iteration)
        // ---- B fragments for this chunk (issued before prefetch DMA) ----
        const int k8 = (c0>>3) + quad;
        short8 Bh[TN], Bl[TN];
#pragma unroll
        for(int nt=0;nt<TN;nt++){
            int n = wn*(NP/2) + nt*16 + l15;
            size_t off = ((size_t)k8*NP + n)*8;
            Bh[nt] = *(const short8*)(wh + off);
            Bl[nt] = *(const short8*)(wl + off);
        }
        // ---- prefetch next chunk into the other buffer ----
        if(c0+32 < K0) stage(c0+32, pb^1);
        // ---- depthwise 3x3 + split to bf16 hi/lo ----
        const float* xp = &xs[pb][0];
        const float* dwc = &dwls[pb][0];
#pragma unroll
        for(int r=0;r<4;r++){
            int idx = r*256 + tid;
            int c4 = idx&7, px = idx>>3;
            int py = px>>4, pxx = px&15;
            float4 s = {0.f,0.f,0.f,0.f};
#pragma unroll
            for(int kh=0;kh<3;kh++)
#pragma unroll
                for(int kw=0;kw<3;kw++){
                    float4 xv = *(const float4*)&xp[((py+kh)*18 + (pxx+kw))*36 + c4*4];
                    float4 wv4= *(const float4*)&dwc[(kh*3+kw)*32 + c4*4];
                    s.x = fmaf(xv.x,wv4.x,s.x); s.y = fmaf(xv.y,wv4.y,s.y);
                    s.z = fmaf(xv.z,wv4.z,s.z); s.w = fmaf(xv.w,wv4.w,s.w);
                }
            short h0=bf16h(s.x), h1=bf16h(s.y), h2=bf16h(s.z), h3=bf16h(s.w);
            short l0=bf16h(s.x-bf16f(h0)), l1=bf16h(s.y-bf16f(h1));
            short l2=bf16h(s.z-bf16f(h2)), l3=bf16h(s.w-bf16f(h3));
            int base = (c4>>1)*1024 + px*8 + (c4&1)*4;
            *(short4*)&dshh[base] = make_short4(h0,h1,h2,h3);
            *(short4*)&dshl[base] = make_short4(l0,l1,l2,l3);
        }
        lds_barrier();     // orders dsh writes/reads; DMA keeps flying
        // ---- MFMA: A from LDS, B from registers ----
#pragma unroll
        for(int i=0;i<4;i++){
            int ab = quad*1024 + (wm*64 + i*16 + l15)*8;
            short8 Ah = *(const short8*)&dshh[ab];
            short8 Al = *(const short8*)&dshl[ab];
#pragma unroll
            for(int nt=0;nt<TN;nt++){
                f32x4 c = acc[i][nt];
                c = __builtin_amdgcn_mfma_f32_16x16x32_bf16(Ah,Bh[nt],c,0,0,0);
                c = __builtin_amdgcn_mfma_f32_16x16x32_bf16(Al,Bh[nt],c,0,0,0);
                c = __builtin_amdgcn_mfma_f32_16x16x32_bf16(Ah,Bl[nt],c,0,0,0);
                acc[i][nt] = c;
            }
        }
        lds_barrier();     // dsh reads done before next chunk's dw writes
        pb ^= 1;
    }
    // ---- epilogue: bias + mish + store ----
#pragma unroll
    for(int i=0;i<4;i++){
        int pxb = wm*64 + i*16 + quad*4;
#pragma unroll
        for(int nt=0;nt<TN;nt++){
            int cout = wn*(NP/2) + nt*16 + l15;
            if(cout < COUT){
                float bv = BIAS ? bias[cout] : 0.f;
#pragma unroll
                for(int r=0;r<4;r++){
                    int p = pxb + r;
                    int y = y0 + (p>>4), x = x0 + (p&15);
                    float v = acc[i][nt][r] + bv;
                    if(ACT) v = mish_f(v);
                    out[(((size_t)b*HH + y)*WW + x)*COUT + cout] = v;
                }
            }
        }
    }
}

// ---------------------------------------------------------------------------
extern "C" void kernel_launch(void* const* d_in, const int* in_sizes, int n_in,
                              void* d_out, int out_size, void* d_ws, size_t ws_size,
                              hipStream_t stream)
{
    (void)in_sizes; (void)n_in; (void)out_size;
    const float* prv = (const float*)d_in[0];
    const float* nxt = (const float*)d_in[1];
    const float* dws[6] = {(const float*)d_in[2],(const float*)d_in[5],(const float*)d_in[8],
                           (const float*)d_in[11],(const float*)d_in[14],(const float*)d_in[17]};
    const float* pws[6] = {(const float*)d_in[3],(const float*)d_in[6],(const float*)d_in[9],
                           (const float*)d_in[12],(const float*)d_in[15],(const float*)d_in[18]};
    const float* b0  = (const float*)d_in[4];
    const float* b1  = (const float*)d_in[7];
    const float* b2  = (const float*)d_in[10];
    const float* b3  = (const float*)d_in[13];
    const float* b4  = (const float*)d_in[16];

    // ---- weight slabs: pw hi/lo bf16 + dw fp32 [9][K0] + zero scratch ----
    const int   Ks[6]   = {337,128,128, 96, 64, 32};
    const int   K0s[6]  = {352,128,128, 96, 64, 32};
    const int   Ns[6]   = {128,128, 96, 64, 32,  2};
    const int   NPs[6]  = {128,128, 96, 64, 32, 32};
    const int   rmp[6]  = {  1,  0,  0,  0,  0,  0};
    size_t offs[6]; size_t E = 0;
    for(int i=0;i<6;i++){ offs[i] = E; E += (size_t)K0s[i]*NPs[i]; }
    size_t dwoffs[6]; size_t Edw = 0;
    for(int i=0;i<6;i++){ dwoffs[i] = Edw; Edw += (size_t)9*K0s[i]; }

    short* Whs = (short*)d_ws;
    short* Wls = Whs + E;
    float* Dwp = (float*)((char*)d_ws + ((E*2*sizeof(short) + 255) & ~(size_t)255));
    float* Zb  = Dwp + Edw;                    // 64-float zero scratch
    size_t wbytes = (((char*)(Zb + 64) - (char*)d_ws) + 255) & ~(size_t)255;

    zero_k<<<1,64,0,stream>>>(Zb, 64);
    for(int i=0;i<6;i++){
        int total = K0s[i]*NPs[i];
        prep_pw<<<(total+255)/256,256,0,stream>>>(pws[i], Whs+offs[i], Wls+offs[i],
                                                  Ks[i], Ns[i], NPs[i], total, rmp[i]);
        int tdw = 9*K0s[i];
        prep_dw<<<(tdw+255)/256,256,0,stream>>>(dws[i], Dwp+dwoffs[i],
                                                Ks[i], K0s[i], rmp[i], tdw);
    }

    // ---- activation buffers, batch-chunked ----
    const size_t per_batch_floats = (size_t)HWPIX * (NSP + 128 + 128);
    size_t avail = (ws_size > wbytes) ? (ws_size - wbytes) : 0;
    int NB = (int)(avail / (per_batch_floats * sizeof(float)));
    if(NB > BATCH) NB = BATCH;
    if(NB < 1)     NB = 1;
    while(BATCH % NB) NB--;

    float* fbase = (float*)((char*)d_ws + wbytes);
    float* costb = fbase;
    float* bufA  = costb + (size_t)NB*HWPIX*NSP;
    float* bufB  = bufA  + (size_t)NB*HWPIX*128;

    for(int bb=0; bb<BATCH; bb+=NB){
        const float* prv_o = prv + (size_t)bb*HWPIX*CC;
        const float* nxt_o = nxt + (size_t)bb*HWPIX*CC;
        float*       out_o = (float*)d_out + (size_t)bb*HWPIX*2;
        dim3 gc(WW/16, HH/16, NB);
        dim3 gs(WW/16, HH/8,  NB);

        cost_kernel<<<gc,256,0,stream>>>(prv_o, nxt_o, Zb, costb);
        sep_mfma<337,352,128,128,true ,true ,true ><<<gs,256,0,stream>>>(nullptr, costb, prv_o, nxt_o, Dwp+dwoffs[0], Whs+offs[0], Wls+offs[0], b0, Zb, bufA);
        sep_mfma<128,128,128,128,true ,true ,false><<<gs,256,0,stream>>>(bufA, nullptr,nullptr,nullptr, Dwp+dwoffs[1], Whs+offs[1], Wls+offs[1], b1, Zb, bufB);
        sep_mfma<128,128, 96, 96,true ,true ,false><<<gs,256,0,stream>>>(bufB, nullptr,nullptr,nullptr, Dwp+dwoffs[2], Whs+offs[2], Wls+offs[2], b2, Zb, bufA);
        sep_mfma< 96, 96, 64, 64,true ,true ,false><<<gs,256,0,stream>>>(bufA, nullptr,nullptr,nullptr, Dwp+dwoffs[3], Whs+offs[3], Wls+offs[3], b3, Zb, bufB);
        sep_mfma< 64, 64, 32, 32,true ,true ,false><<<gs,256,0,stream>>>(bufB, nullptr,nullptr,nullptr, Dwp+dwoffs[4], Whs+offs[4], Wls+offs[4], b4, Zb, bufA);
        sep_mfma< 32, 32,  2, 32,false,false,false><<<gs,256,0,stream>>>(bufA, nullptr,nullptr,nullptr, Dwp+dwoffs[5], Whs+offs[5], Wls+offs[5], nullptr, Zb, out_o);
    }
}